// Round 1
// baseline (773.870 us; speedup 1.0000x reference)
//
#include <hip/hip_runtime.h>

#define NUM_NODES 100000
#define GAMMA 0.5f

// K1: scatter-add mask values and counts into per-node accumulators.
__global__ void scatter_sum_kernel(const float* __restrict__ mask,
                                   const int* __restrict__ src,
                                   float* __restrict__ sums,
                                   float* __restrict__ cnts,
                                   int E) {
    int i = blockIdx.x * blockDim.x + threadIdx.x;
    if (i < E) {
        int s = src[i];
        float m = mask[i];
        atomicAdd(&sums[s], m);
        atomicAdd(&cnts[s], 1.0f);
    }
}

// K2: finalize per-node mean with clamp(count, min=1).
__global__ void avg_kernel(const float* __restrict__ sums,
                           const float* __restrict__ cnts,
                           float* __restrict__ avg,
                           int N) {
    int i = blockIdx.x * blockDim.x + threadIdx.x;
    if (i < N) {
        avg[i] = sums[i] / fmaxf(cnts[i], 1.0f);
    }
}

// K3: gather endpoint means, blend with original mask.
__global__ void smooth_kernel(const float* __restrict__ mask,
                              const int* __restrict__ src,
                              const int* __restrict__ dst,
                              const float* __restrict__ avg,
                              float* __restrict__ out,
                              int E) {
    int i = blockIdx.x * blockDim.x + threadIdx.x;
    if (i < E) {
        float sm = 0.5f * (avg[src[i]] + avg[dst[i]]);
        out[i] = (1.0f - GAMMA) * mask[i] + GAMMA * sm;
    }
}

extern "C" void kernel_launch(void* const* d_in, const int* in_sizes, int n_in,
                              void* d_out, int out_size, void* d_ws, size_t ws_size,
                              hipStream_t stream) {
    const float* mask = (const float*)d_in[0];
    const int* edge_index = (const int*)d_in[1];
    const int E = in_sizes[0];            // 6,400,000
    const int* src = edge_index;          // row 0
    const int* dst = edge_index + E;      // row 1

    float* sums = (float*)d_ws;                // [NUM_NODES]
    float* cnts = sums + NUM_NODES;            // [NUM_NODES]
    float* avg  = cnts + NUM_NODES;            // [NUM_NODES]
    float* out  = (float*)d_out;

    // zero the accumulators (ws is poisoned 0xAA before every timed call)
    hipMemsetAsync(d_ws, 0, 2 * NUM_NODES * sizeof(float), stream);

    const int B = 256;
    scatter_sum_kernel<<<(E + B - 1) / B, B, 0, stream>>>(mask, src, sums, cnts, E);
    avg_kernel<<<(NUM_NODES + B - 1) / B, B, 0, stream>>>(sums, cnts, avg, NUM_NODES);
    smooth_kernel<<<(E + B - 1) / B, B, 0, stream>>>(mask, src, dst, avg, out, E);
}

// Round 2
// 426.582 us; speedup vs baseline: 1.8141x; 1.8141x over previous
//
#include <hip/hip_runtime.h>

#define NUM_NODES 100000
#define GAMMA 0.5f

// Packed accumulator: bits [63:40] = count, bits [39:0] = fixed-point sum
// (scale 2^24). mask in [0,1), per-node degree << 65536 -> no overflow.
#define FIX_SCALE 16777216.0f
#define SUM_MASK 0xFFFFFFFFFFULL
#define CNT_ONE (1ULL << 40)

// K1: one packed 64-bit atomic per edge (sum + count fused).
__global__ void scatter_sum_kernel(const float* __restrict__ mask,
                                   const int* __restrict__ src,
                                   unsigned long long* __restrict__ acc,
                                   int E) {
    int i4 = blockIdx.x * blockDim.x + threadIdx.x;
    int base = i4 * 4;
    if (base + 3 < E) {
        int4 s = *(const int4*)(src + base);
        float4 m = *(const float4*)(mask + base);
        atomicAdd(&acc[s.x], CNT_ONE | (unsigned long long)(unsigned)(m.x * FIX_SCALE + 0.5f));
        atomicAdd(&acc[s.y], CNT_ONE | (unsigned long long)(unsigned)(m.y * FIX_SCALE + 0.5f));
        atomicAdd(&acc[s.z], CNT_ONE | (unsigned long long)(unsigned)(m.z * FIX_SCALE + 0.5f));
        atomicAdd(&acc[s.w], CNT_ONE | (unsigned long long)(unsigned)(m.w * FIX_SCALE + 0.5f));
    } else {
        for (int i = base; i < E; ++i) {
            atomicAdd(&acc[src[i]],
                      CNT_ONE | (unsigned long long)(unsigned)(mask[i] * FIX_SCALE + 0.5f));
        }
    }
}

// K2: unpack count/sum, finalize mean with clamp(count, min=1).
__global__ void avg_kernel(const unsigned long long* __restrict__ acc,
                           float* __restrict__ avg,
                           int N) {
    int i = blockIdx.x * blockDim.x + threadIdx.x;
    if (i < N) {
        unsigned long long p = acc[i];
        float cnt = (float)(unsigned)(p >> 40);
        float sum = (float)(p & SUM_MASK) * (1.0f / FIX_SCALE);
        avg[i] = sum / fmaxf(cnt, 1.0f);
    }
}

// K3: gather endpoint means, blend with original mask. Vectorized streams.
__global__ void smooth_kernel(const float* __restrict__ mask,
                              const int* __restrict__ src,
                              const int* __restrict__ dst,
                              const float* __restrict__ avg,
                              float* __restrict__ out,
                              int E) {
    int i4 = blockIdx.x * blockDim.x + threadIdx.x;
    int base = i4 * 4;
    if (base + 3 < E) {
        int4 s = *(const int4*)(src + base);
        int4 d = *(const int4*)(dst + base);
        float4 m = *(const float4*)(mask + base);
        float4 o;
        o.x = (1.0f - GAMMA) * m.x + GAMMA * 0.5f * (avg[s.x] + avg[d.x]);
        o.y = (1.0f - GAMMA) * m.y + GAMMA * 0.5f * (avg[s.y] + avg[d.y]);
        o.z = (1.0f - GAMMA) * m.z + GAMMA * 0.5f * (avg[s.z] + avg[d.z]);
        o.w = (1.0f - GAMMA) * m.w + GAMMA * 0.5f * (avg[s.w] + avg[d.w]);
        *(float4*)(out + base) = o;
    } else {
        for (int i = base; i < E; ++i) {
            out[i] = (1.0f - GAMMA) * mask[i] + GAMMA * 0.5f * (avg[src[i]] + avg[dst[i]]);
        }
    }
}

extern "C" void kernel_launch(void* const* d_in, const int* in_sizes, int n_in,
                              void* d_out, int out_size, void* d_ws, size_t ws_size,
                              hipStream_t stream) {
    const float* mask = (const float*)d_in[0];
    const int* edge_index = (const int*)d_in[1];
    const int E = in_sizes[0];            // 6,400,000
    const int* src = edge_index;          // row 0
    const int* dst = edge_index + E;      // row 1

    unsigned long long* acc = (unsigned long long*)d_ws;   // [NUM_NODES]
    float* avg = (float*)(acc + NUM_NODES);                // [NUM_NODES]
    float* out = (float*)d_out;

    hipMemsetAsync(d_ws, 0, NUM_NODES * sizeof(unsigned long long), stream);

    const int B = 256;
    const int E4 = (E + 3) / 4;
    scatter_sum_kernel<<<(E4 + B - 1) / B, B, 0, stream>>>(mask, src, acc, E);
    avg_kernel<<<(NUM_NODES + B - 1) / B, B, 0, stream>>>(acc, avg, NUM_NODES);
    smooth_kernel<<<(E4 + B - 1) / B, B, 0, stream>>>(mask, src, dst, avg, out, E);
}

// Round 3
// 239.435 us; speedup vs baseline: 3.2321x; 1.7816x over previous
//
#include <hip/hip_runtime.h>

#define NUM_NODES 100000
#define P 8
#define NPART 12500             // NUM_NODES / P
#define GAMMA 0.5f

// 32-bit packed partial: bits [31:22] = count (max 1023), bits [21:0] =
// fixed-point sum, scale 2^14 (max representable sum 256; per-chunk node
// degree is ~1 on average, <<256 worst case). mask in [0,1).
#define SCALE 16384.0f
#define INV_SCALE (1.0f / 16384.0f)
#define CNT_ONE (1u << 22)
#define SUM_MASK ((1u << 22) - 1)

// ---------- main path: partitioned LDS scatter, no global atomics ----------

// Block b = (c, p): c = b / P edge chunk, p = b % P node partition.
// Partition-fastest order so the P blocks sharing chunk c run ~concurrently
// and the chunk's src/mask stream stays L2/L3 resident.
__global__ void part_scatter_kernel(const float* __restrict__ mask,
                                    const int* __restrict__ src,
                                    unsigned* __restrict__ partials,
                                    int E, int CS) {
    __shared__ unsigned tab[NPART];
    const int c = blockIdx.x / P;
    const int p = blockIdx.x % P;
    const int pbase = p * NPART;

    for (int j = threadIdx.x; j < NPART; j += blockDim.x) tab[j] = 0u;
    __syncthreads();

    const int start = c * CS;
    const int end = min(E, start + CS);
    const int nquads = (end - start) >> 2;

    for (int q = threadIdx.x; q < nquads; q += blockDim.x) {
        const int i = start + q * 4;
        int4 s = *(const int4*)(src + i);
        float4 m = *(const float4*)(mask + i);
        int sx = s.x - pbase;
        if ((unsigned)sx < NPART) atomicAdd(&tab[sx], CNT_ONE | (unsigned)(m.x * SCALE + 0.5f));
        int sy = s.y - pbase;
        if ((unsigned)sy < NPART) atomicAdd(&tab[sy], CNT_ONE | (unsigned)(m.y * SCALE + 0.5f));
        int sz = s.z - pbase;
        if ((unsigned)sz < NPART) atomicAdd(&tab[sz], CNT_ONE | (unsigned)(m.z * SCALE + 0.5f));
        int sw = s.w - pbase;
        if ((unsigned)sw < NPART) atomicAdd(&tab[sw], CNT_ONE | (unsigned)(m.w * SCALE + 0.5f));
    }
    // tail (< 4 edges of the chunk)
    for (int i = start + nquads * 4 + threadIdx.x; i < end; i += blockDim.x) {
        int sx = src[i] - pbase;
        if ((unsigned)sx < NPART)
            atomicAdd(&tab[sx], CNT_ONE | (unsigned)(mask[i] * SCALE + 0.5f));
    }

    __syncthreads();
    unsigned* dst = partials + (size_t)blockIdx.x * NPART;
    for (int j = threadIdx.x; j < NPART; j += blockDim.x) dst[j] = tab[j];
}

// K2: reduce C partials per node, finalize mean with clamp(count, min=1).
__global__ void reduce_avg_kernel(const unsigned* __restrict__ partials,
                                  float* __restrict__ avg,
                                  int C) {
    int n = blockIdx.x * blockDim.x + threadIdx.x;
    if (n < NUM_NODES) {
        int p = n / NPART;
        int loc = n - p * NPART;
        const unsigned* base = partials + (size_t)p * NPART + loc;
        unsigned cnt = 0, sum = 0;
        const size_t stride = (size_t)P * NPART;
        for (int c = 0; c < C; ++c) {
            unsigned v = base[(size_t)c * stride];
            cnt += v >> 22;
            sum += v & SUM_MASK;
        }
        avg[n] = ((float)sum * INV_SCALE) / fmaxf((float)cnt, 1.0f);
    }
}

// K3: gather endpoint means, blend with original mask. Vectorized streams.
__global__ void smooth_kernel(const float* __restrict__ mask,
                              const int* __restrict__ src,
                              const int* __restrict__ dst,
                              const float* __restrict__ avg,
                              float* __restrict__ out,
                              int E) {
    int i4 = blockIdx.x * blockDim.x + threadIdx.x;
    int base = i4 * 4;
    if (base + 3 < E) {
        int4 s = *(const int4*)(src + base);
        int4 d = *(const int4*)(dst + base);
        float4 m = *(const float4*)(mask + base);
        float4 o;
        o.x = (1.0f - GAMMA) * m.x + GAMMA * 0.5f * (avg[s.x] + avg[d.x]);
        o.y = (1.0f - GAMMA) * m.y + GAMMA * 0.5f * (avg[s.y] + avg[d.y]);
        o.z = (1.0f - GAMMA) * m.z + GAMMA * 0.5f * (avg[s.z] + avg[d.z]);
        o.w = (1.0f - GAMMA) * m.w + GAMMA * 0.5f * (avg[s.w] + avg[d.w]);
        *(float4*)(out + base) = o;
    } else {
        for (int i = base; i < E; ++i) {
            out[i] = (1.0f - GAMMA) * mask[i] + GAMMA * 0.5f * (avg[src[i]] + avg[dst[i]]);
        }
    }
}

// ---------- fallback path (small ws): R2 packed 64-bit atomic scatter ------

#define FIX_SCALE64 16777216.0f
#define SUM_MASK64 0xFFFFFFFFFFULL
#define CNT_ONE64 (1ULL << 40)

__global__ void scatter_sum_kernel(const float* __restrict__ mask,
                                   const int* __restrict__ src,
                                   unsigned long long* __restrict__ acc,
                                   int E) {
    int i4 = blockIdx.x * blockDim.x + threadIdx.x;
    int base = i4 * 4;
    if (base + 3 < E) {
        int4 s = *(const int4*)(src + base);
        float4 m = *(const float4*)(mask + base);
        atomicAdd(&acc[s.x], CNT_ONE64 | (unsigned long long)(unsigned)(m.x * FIX_SCALE64 + 0.5f));
        atomicAdd(&acc[s.y], CNT_ONE64 | (unsigned long long)(unsigned)(m.y * FIX_SCALE64 + 0.5f));
        atomicAdd(&acc[s.z], CNT_ONE64 | (unsigned long long)(unsigned)(m.z * FIX_SCALE64 + 0.5f));
        atomicAdd(&acc[s.w], CNT_ONE64 | (unsigned long long)(unsigned)(m.w * FIX_SCALE64 + 0.5f));
    } else {
        for (int i = base; i < E; ++i) {
            atomicAdd(&acc[src[i]],
                      CNT_ONE64 | (unsigned long long)(unsigned)(mask[i] * FIX_SCALE64 + 0.5f));
        }
    }
}

__global__ void avg_kernel(const unsigned long long* __restrict__ acc,
                           float* __restrict__ avg,
                           int N) {
    int i = blockIdx.x * blockDim.x + threadIdx.x;
    if (i < N) {
        unsigned long long pk = acc[i];
        float cnt = (float)(unsigned)(pk >> 40);
        float sum = (float)(pk & SUM_MASK64) * (1.0f / FIX_SCALE64);
        avg[i] = sum / fmaxf(cnt, 1.0f);
    }
}

// ---------------------------------------------------------------------------

extern "C" void kernel_launch(void* const* d_in, const int* in_sizes, int n_in,
                              void* d_out, int out_size, void* d_ws, size_t ws_size,
                              hipStream_t stream) {
    const float* mask = (const float*)d_in[0];
    const int* edge_index = (const int*)d_in[1];
    const int E = in_sizes[0];            // 6,400,000
    const int* src = edge_index;          // row 0
    const int* dst = edge_index + E;      // row 1
    float* out = (float*)d_out;

    const int B = 256;
    const int E4 = (E + 3) / 4;

    // Adaptive chunk count from ws budget (constant across calls -> same work
    // every call). Layout: [partials: C*P*NPART u32][avg: NUM_NODES f32]
    const size_t avg_bytes = (size_t)NUM_NODES * sizeof(float);
    const size_t table_bytes = (size_t)P * NPART * sizeof(unsigned);
    int C = 0;
    if (ws_size > avg_bytes + table_bytes) {
        C = (int)((ws_size - avg_bytes) / table_bytes);
        if (C > 96) C = 96;
    }

    if (C >= 16) {
        unsigned* partials = (unsigned*)d_ws;
        float* avg = (float*)((char*)d_ws + (size_t)C * table_bytes);
        const int CS = (E + C - 1) / C;
        part_scatter_kernel<<<C * P, B, 0, stream>>>(mask, src, partials, E, CS);
        reduce_avg_kernel<<<(NUM_NODES + B - 1) / B, B, 0, stream>>>(partials, avg, C);
        smooth_kernel<<<(E4 + B - 1) / B, B, 0, stream>>>(mask, src, dst, avg, out, E);
    } else {
        // fallback: packed 64-bit device atomics (R2 path)
        unsigned long long* acc = (unsigned long long*)d_ws;   // [NUM_NODES]
        float* avg = (float*)(acc + NUM_NODES);                // [NUM_NODES]
        hipMemsetAsync(d_ws, 0, NUM_NODES * sizeof(unsigned long long), stream);
        scatter_sum_kernel<<<(E4 + B - 1) / B, B, 0, stream>>>(mask, src, acc, E);
        avg_kernel<<<(NUM_NODES + B - 1) / B, B, 0, stream>>>(acc, avg, NUM_NODES);
        smooth_kernel<<<(E4 + B - 1) / B, B, 0, stream>>>(mask, src, dst, avg, out, E);
    }
}